// Round 4
// baseline (735.718 us; speedup 1.0000x reference)
//
#include <hip/hip_runtime.h>

// GAT (3-layer) on MI355X. N=50000 nodes, E=800000 edges, D=64, H=2/2/1.
// R4: agg softmax without max-subtraction (add-only butterfly, no exp in merge),
//     first-chunk numerator reuse; GEMM 64-row blocks w/ col-pair layout,
//     fused embedding gather (L0) + fused el/er epilogue. 12 dispatches.

__device__ __forceinline__ float lrelu(float x){ return x >= 0.f ? x : 0.2f*x; }

__device__ __forceinline__ unsigned short f2bf(float f){   // RNE round
  unsigned int u = __float_as_uint(f);
  u += 0x7fffu + ((u >> 16) & 1u);
  return (unsigned short)(u >> 16);
}
__device__ __forceinline__ float bf2f(unsigned short u){
  return __uint_as_float((unsigned int)u << 16);
}
__device__ __forceinline__ float rl_f(float v, int l){
  return __int_as_float(__builtin_amdgcn_readlane(__float_as_int(v), l));
}

__global__ void k_zero_i32(int* __restrict__ p, int n){
  int i = blockIdx.x*blockDim.x + threadIdx.x;
  if (i < n) p[i] = 0;
}

__global__ void k_hist(const int* __restrict__ dst, int* __restrict__ counts, int E){
  int i = blockIdx.x*blockDim.x + threadIdx.x;
  if (i < E) atomicAdd(&counts[dst[i]], 1);
}

__global__ void k_scan_local(const int* __restrict__ counts, int* __restrict__ row_ptr,
                             int* __restrict__ bsum, int N){
  __shared__ int s[256];
  int t = threadIdx.x, g = blockIdx.x*256 + t;
  int v = (g < N) ? counts[g] : 0;
  s[t] = v; __syncthreads();
  #pragma unroll
  for (int off = 1; off < 256; off <<= 1){
    int x = 0;
    if (t >= off) x = s[t-off];
    __syncthreads();
    s[t] += x;
    __syncthreads();
  }
  if (g < N) row_ptr[g+1] = s[t];
  if (g == 0 && t == 0) row_ptr[0] = 0;
  if (t == 255) bsum[blockIdx.x] = s[255];
}

__global__ void k_scan_top(int* __restrict__ bsum, int nb){
  __shared__ int s[256];
  int t = threadIdx.x;
  int v = (t < nb) ? bsum[t] : 0;
  s[t] = v; __syncthreads();
  #pragma unroll
  for (int off = 1; off < 256; off <<= 1){
    int x = 0;
    if (t >= off) x = s[t-off];
    __syncthreads();
    s[t] += x;
    __syncthreads();
  }
  if (t < nb) bsum[t] = s[t] - v;  // exclusive block offsets
}

__global__ void k_scan_fix(int* __restrict__ row_ptr, const int* __restrict__ bsum, int N){
  int g = blockIdx.x*256 + threadIdx.x;
  if (g < N && blockIdx.x > 0) row_ptr[g+1] += bsum[blockIdx.x];
}

__global__ void k_scatter(const int* __restrict__ src, const int* __restrict__ dst,
                          const int* __restrict__ row_ptr, int* __restrict__ cursor,
                          int* __restrict__ ssrc, int E){
  int i = blockIdx.x*blockDim.x + threadIdx.x;
  if (i >= E) return;
  int d = dst[i];
  int pos = atomicAdd(&cursor[d], 1);
  ssrc[row_ptr[d] + pos] = src[i];
}

// fhb[N][128](bf16, packed dwords: lane l holds cols 2l,2l+1) = h @ W (+split Wr cols 64..127).
// elr[n][4] = {el_h0, el_h1, er_h0, er_h1} fused in epilogue.
// Block: 256 thr = 4 waves, 64 rows; wave w: rows 16w..16w+15.
template<int IN, int H, bool EMBED, bool SPLITW>
__global__ __launch_bounds__(256) void k_gemm(
    const float* __restrict__ h,
    const int* __restrict__ feat, const float* __restrict__ fv, const float* __restrict__ emb,
    const float* __restrict__ W, const float* __restrict__ Wr,
    const float* __restrict__ al, const float* __restrict__ ar,
    unsigned* __restrict__ fhb, float* __restrict__ elr, int N){
  __shared__ float hs[64][IN + 4];       // [r][k], b128 broadcast reads along k
  __shared__ float2 Wp[32][64];          // [kk][lane] = (W[:,2l], W[:,2l+1])
  __shared__ int   sfeat[64];
  __shared__ float sfv[64];
  const int t = threadIdx.x;
  const int lane = t & 63, wid = t >> 6;
  const int row0 = blockIdx.x * 64;
  const int wld = SPLITW ? 64 : 128;

  if (EMBED){
    if (t < 64){
      int row = row0 + t;
      sfeat[t] = (row < N) ? feat[row]*64 : 0;
      sfv[t]   = (row < N) ? fv[row] : 0.f;
    }
    __syncthreads();
    for (int id = t; id < 64*(IN/4); id += 256){
      int r = id / (IN/4), c4 = id % (IN/4);
      float4 v = make_float4(0.f,0.f,0.f,0.f);
      if (row0 + r < N){
        v = ((const float4*)(emb + sfeat[r]))[c4];
        float sc = sfv[r];
        v.x *= sc; v.y *= sc; v.z *= sc; v.w *= sc;
      }
      *(float4*)&hs[r][c4*4] = v;
    }
  } else {
    for (int id = t; id < 64*(IN/4); id += 256){
      int r = id / (IN/4), c4 = id % (IN/4);
      int row = row0 + r;
      float4 v = make_float4(0.f,0.f,0.f,0.f);
      if (row < N) v = ((const float4*)(h + (size_t)row*IN))[c4];
      *(float4*)&hs[r][c4*4] = v;
    }
  }

  float2 acc[16];
  #pragma unroll
  for (int j = 0; j < 16; j++) acc[j] = make_float2(0.f, 0.f);

  for (int kb = 0; kb < IN; kb += 32){
    __syncthreads();
    for (int id = t; id < 32*64; id += 256){
      int kk = id >> 6, l = id & 63;
      const float* wb = SPLITW ? (l < 32 ? W + 2*l : Wr + (2*l - 64)) : W + 2*l;
      Wp[kk][l] = *(const float2*)(wb + (size_t)(kb + kk)*wld);
    }
    __syncthreads();
    for (int kk = 0; kk < 32; kk += 4){
      float4 hv[16];
      #pragma unroll
      for (int j = 0; j < 16; j++) hv[j] = *(const float4*)&hs[wid*16 + j][kb + kk];
      #pragma unroll
      for (int u = 0; u < 4; u++){
        float2 wv = Wp[kk + u][lane];
        #pragma unroll
        for (int j = 0; j < 16; j++){
          float x = (&hv[j].x)[u];
          acc[j].x += x * wv.x;
          acc[j].y += x * wv.y;
        }
      }
    }
  }

  // epilogue: bf16 pack-store + fused el/er (heads live in 32-lane halves)
  float2 alv = make_float2(0.f,0.f), arv = make_float2(0.f,0.f);
  if (2*lane < H*64){
    alv = ((const float2*)al)[lane];
    arv = ((const float2*)ar)[lane];
  }
  #pragma unroll
  for (int j = 0; j < 16; j++){
    int row = row0 + wid*16 + j;   // wave-uniform
    if (row >= N) continue;
    unsigned pk = (unsigned)f2bf(acc[j].x) | ((unsigned)f2bf(acc[j].y) << 16);
    fhb[(size_t)row*64 + lane] = pk;
    float pel = acc[j].x*alv.x + acc[j].y*alv.y;
    float per = acc[j].x*arv.x + acc[j].y*arv.y;
    #pragma unroll
    for (int off = 16; off >= 1; off >>= 1){   // reduce within 32-lane halves
      pel += __shfl_xor(pel, off, 64);
      per += __shfl_xor(per, off, 64);
    }
    if (lane == 0){ elr[row*4+0] = pel; elr[row*4+2] = per; }
    if (lane == 32){
      elr[row*4+1] = (H == 2) ? pel : 0.f;
      elr[row*4+3] = (H == 2) ? per : 0.f;
    }
  }
}

// One wave per dst node. Pass 1: flat exp-sum (no max; logits bounded, clamp 30).
// Pass 2: readlane broadcast + 8-deep gather; first chunk reuses pass-1 numerators.
template<int H>
__global__ __launch_bounds__(256) void k_agg(
    const unsigned* __restrict__ fhb, const float* __restrict__ elr,
    const int* __restrict__ row_ptr, const int* __restrict__ ssrc,
    const float* __restrict__ bias, const float* __restrict__ res,
    int act, int res_from_fh,
    float* __restrict__ out, int out_ld, int N){
  int lane = threadIdx.x & 63, wid = threadIdx.x >> 6;
  int n = blockIdx.x*4 + wid;
  if (n >= N) return;
  int beg = row_ptr[n], end = row_ptr[n+1];
  float er0 = elr[n*4+2];
  float er1 = (H == 2) ? elr[n*4+3] : 0.f;

  // pass 1: numerators + denominator (softmax is shift-invariant; no max needed)
  float x0 = 0.f, x1 = 0.f;
  {
    int i = beg + lane;
    if (i < end){
      int s = ssrc[i];
      float2 el = *(const float2*)(elr + s*4);
      x0 = __expf(fminf(lrelu(el.x + er0), 30.f));
      if (H == 2) x1 = __expf(fminf(lrelu(el.y + er1), 30.f));
    }
  }
  float d0 = x0, d1 = x1;
  for (int i = beg + lane + 64; i < end; i += 64){
    int s = ssrc[i];
    float2 el = *(const float2*)(elr + s*4);
    d0 += __expf(fminf(lrelu(el.x + er0), 30.f));
    if (H == 2) d1 += __expf(fminf(lrelu(el.y + er1), 30.f));
  }
  #pragma unroll
  for (int off = 32; off >= 1; off >>= 1){       // add-only butterfly
    d0 += __shfl_xor(d0, off, 64);
    if (H == 2) d1 += __shfl_xor(d1, off, 64);
  }
  float rd0 = d0 > 0.f ? 1.f/d0 : 0.f;
  float rd1 = (H == 2 && d1 > 0.f) ? 1.f/d1 : 0.f;

  // pass 2
  float ax = 0.f, ay = 0.f;
  for (int base = beg; base < end; base += 64){
    int i = base + lane;
    int s = 0; float a0 = 0.f, a1 = 0.f;
    if (i < end){
      s = ssrc[i];
      if (base == beg){
        a0 = x0 * rd0; if (H == 2) a1 = x1 * rd1;
      } else {
        float2 el = *(const float2*)(elr + s*4);
        a0 = __expf(fminf(lrelu(el.x + er0), 30.f)) * rd0;
        if (H == 2) a1 = __expf(fminf(lrelu(el.y + er1), 30.f)) * rd1;
      }
    }
    int cnt  = min(64, end - base);
    int cnt8 = (cnt + 7) & ~7;          // pad lanes have a=0, s=0 -> contribute 0
    if (H == 2){
      for (int j0 = 0; j0 < cnt8; j0 += 8){
        unsigned w[8]; float aj[8];
        #pragma unroll
        for (int u = 0; u < 8; u++){
          int sj = __builtin_amdgcn_readlane(s, j0 + u);      // SGPR: scalar addr
          w[u] = fhb[(size_t)sj*64 + lane];                   // cols 2l,2l+1
        }
        #pragma unroll
        for (int u = 0; u < 8; u++){
          float aj0 = rl_f(a0, j0 + u);
          float aj1 = rl_f(a1, j0 + u);
          aj[u] = (lane < 32) ? aj0 : aj1;                    // head = 2l/64
        }
        #pragma unroll
        for (int u = 0; u < 8; u++){
          ax += bf2f((unsigned short)(w[u] & 0xffffu)) * aj[u];
          ay += bf2f((unsigned short)(w[u] >> 16))     * aj[u];
        }
      }
    } else {
      const unsigned short* fh16 = (const unsigned short*)fhb;
      for (int j0 = 0; j0 < cnt8; j0 += 8){
        unsigned short w[8]; float aj[8];
        #pragma unroll
        for (int u = 0; u < 8; u++){
          int sj = __builtin_amdgcn_readlane(s, j0 + u);
          w[u] = fh16[(size_t)sj*128 + lane];                 // cols 0..63
        }
        #pragma unroll
        for (int u = 0; u < 8; u++) aj[u] = rl_f(a0, j0 + u);
        #pragma unroll
        for (int u = 0; u < 8; u++) ax += bf2f(w[u]) * aj[u];
      }
    }
  }
  if (H == 2){
    int c0 = lane*2;
    float o0 = ax + bias[c0], o1 = ay + bias[c0+1];
    if (res){ o0 += res[n*128 + c0]; o1 += res[n*128 + c0+1]; }
    if (act){ o0 = o0 > 0.f ? o0 : expm1f(o0); o1 = o1 > 0.f ? o1 : expm1f(o1); }
    *(float2*)(out + n*out_ld + c0) = make_float2(o0, o1);
  } else {
    const unsigned short* fh16 = (const unsigned short*)fhb;
    float o = ax + bias[lane];
    if (res_from_fh) o += bf2f(fh16[(size_t)n*128 + 64 + lane]);
    out[n*out_ld + lane] = o;
  }
}

extern "C" void kernel_launch(void* const* d_in, const int* in_sizes, int n_in,
                              void* d_out, int out_size, void* d_ws, size_t ws_size,
                              hipStream_t stream) {
  const int*   feat = (const int*)  d_in[0];
  const float* fv   = (const float*)d_in[1];
  const int*   src  = (const int*)  d_in[2];
  const int*   dst  = (const int*)  d_in[3];
  const float* emb  = (const float*)d_in[4];
  const float* W0   = (const float*)d_in[5];
  const float* al0  = (const float*)d_in[6];
  const float* ar0  = (const float*)d_in[7];
  const float* b0   = (const float*)d_in[8];
  const float* W1   = (const float*)d_in[9];
  const float* al1  = (const float*)d_in[10];
  const float* ar1  = (const float*)d_in[11];
  const float* b1   = (const float*)d_in[12];
  const float* W2   = (const float*)d_in[13];
  const float* al2  = (const float*)d_in[14];
  const float* ar2  = (const float*)d_in[15];
  const float* b2   = (const float*)d_in[16];
  const float* rW2  = (const float*)d_in[17];
  const int N = in_sizes[0] / 8;   // 50000
  const int E = in_sizes[2];       // 800000

  size_t off = 0;
  auto alloc = [&](size_t bytes) -> void* {
    void* p = (char*)d_ws + off;
    off = (off + bytes + 255) & ~(size_t)255;
    return p;
  };
  unsigned* P1  = (unsigned*)alloc((size_t)N*64*sizeof(unsigned));   // fh bf16 packed
  float* P2     = (float*)alloc((size_t)N*128*sizeof(float));
  float* P3     = (float*)alloc((size_t)N*128*sizeof(float));
  float* elr    = (float*)alloc((size_t)N*4*sizeof(float));
  int* row_ptr  = (int*)alloc((size_t)(N+1)*sizeof(int));
  int* counts   = (int*)alloc((size_t)2*N*sizeof(int));
  int* cursor   = counts + N;
  int* ssrc     = (int*)alloc((size_t)E*sizeof(int));
  int* bsum     = (int*)alloc(256*sizeof(int));

  int nb1 = (N + 255) / 256;
  // CSR build
  k_zero_i32<<<(2*N + 255)/256, 256, 0, stream>>>(counts, 2*N);
  k_hist<<<(E + 255)/256, 256, 0, stream>>>(dst, counts, E);
  k_scan_local<<<nb1, 256, 0, stream>>>(counts, row_ptr, bsum, N);
  k_scan_top<<<1, 256, 0, stream>>>(bsum, nb1);
  k_scan_fix<<<nb1, 256, 0, stream>>>(row_ptr, bsum, N);
  k_scatter<<<(E + 255)/256, 256, 0, stream>>>(src, dst, row_ptr, cursor, ssrc, E);

  int gt = (N + 63)/64;
  int nagg = (N + 3)/4;
  // layer 0: in=64 (fused embedding), H=2, no residual, elu
  k_gemm<64,2,true,false><<<gt, 256, 0, stream>>>(nullptr, feat, fv, emb,
      W0, nullptr, al0, ar0, P1, elr, N);
  k_agg<2><<<nagg, 256, 0, stream>>>(P1, elr, row_ptr, ssrc, b0, nullptr, 1, 0, P2, 128, N);
  // layer 1: in=128, H=2, identity residual, elu
  k_gemm<128,2,false,false><<<gt, 256, 0, stream>>>(P2, nullptr, nullptr, nullptr,
      W1, nullptr, al1, ar1, P1, elr, N);
  k_agg<2><<<nagg, 256, 0, stream>>>(P1, elr, row_ptr, ssrc, b1, P2, 1, 0, P3, 128, N);
  // layer 2: in=128, H=1, projected residual (cols 64..127 = h@resW2), no act
  k_gemm<128,1,false,true><<<gt, 256, 0, stream>>>(P3, nullptr, nullptr, nullptr,
      W2, rW2, al2, ar2, P1, elr, N);
  k_agg<1><<<nagg, 256, 0, stream>>>(P1, elr, row_ptr, ssrc, b2, nullptr, 0, 1, (float*)d_out, 64, N);
}

// Round 5
// 449.876 us; speedup vs baseline: 1.6354x; 1.6354x over previous
//
#include <hip/hip_runtime.h>

// GAT (3-layer) on MI355X. N=50000 nodes, E=800000 edges, D=64, H=2/2/1.
// R5: R4's fusions (embed gather, el/er epilogue, col-pair bf16, max-free
//     softmax) with GEMM reverted to the register-safe R3 tile:
//     32 rows/block, 8 rows/wave (hv[8]+acc[8] ~ 48 VGPRs of state; R4's
//     16-row/wave tile spilled at 256 VGPRs -> 512MB scratch writes).

__device__ __forceinline__ float lrelu(float x){ return x >= 0.f ? x : 0.2f*x; }

__device__ __forceinline__ unsigned short f2bf(float f){   // RNE round
  unsigned int u = __float_as_uint(f);
  u += 0x7fffu + ((u >> 16) & 1u);
  return (unsigned short)(u >> 16);
}
__device__ __forceinline__ float bf2f(unsigned short u){
  return __uint_as_float((unsigned int)u << 16);
}
__device__ __forceinline__ float rl_f(float v, int l){
  return __int_as_float(__builtin_amdgcn_readlane(__float_as_int(v), l));
}

__global__ void k_zero_i32(int* __restrict__ p, int n){
  int i = blockIdx.x*blockDim.x + threadIdx.x;
  if (i < n) p[i] = 0;
}

__global__ void k_hist(const int* __restrict__ dst, int* __restrict__ counts, int E){
  int i = blockIdx.x*blockDim.x + threadIdx.x;
  if (i < E) atomicAdd(&counts[dst[i]], 1);
}

__global__ void k_scan_local(const int* __restrict__ counts, int* __restrict__ row_ptr,
                             int* __restrict__ bsum, int N){
  __shared__ int s[256];
  int t = threadIdx.x, g = blockIdx.x*256 + t;
  int v = (g < N) ? counts[g] : 0;
  s[t] = v; __syncthreads();
  #pragma unroll
  for (int off = 1; off < 256; off <<= 1){
    int x = 0;
    if (t >= off) x = s[t-off];
    __syncthreads();
    s[t] += x;
    __syncthreads();
  }
  if (g < N) row_ptr[g+1] = s[t];
  if (g == 0 && t == 0) row_ptr[0] = 0;
  if (t == 255) bsum[blockIdx.x] = s[255];
}

__global__ void k_scan_top(int* __restrict__ bsum, int nb){
  __shared__ int s[256];
  int t = threadIdx.x;
  int v = (t < nb) ? bsum[t] : 0;
  s[t] = v; __syncthreads();
  #pragma unroll
  for (int off = 1; off < 256; off <<= 1){
    int x = 0;
    if (t >= off) x = s[t-off];
    __syncthreads();
    s[t] += x;
    __syncthreads();
  }
  if (t < nb) bsum[t] = s[t] - v;  // exclusive block offsets
}

__global__ void k_scan_fix(int* __restrict__ row_ptr, const int* __restrict__ bsum, int N){
  int g = blockIdx.x*256 + threadIdx.x;
  if (g < N && blockIdx.x > 0) row_ptr[g+1] += bsum[blockIdx.x];
}

__global__ void k_scatter(const int* __restrict__ src, const int* __restrict__ dst,
                          const int* __restrict__ row_ptr, int* __restrict__ cursor,
                          int* __restrict__ ssrc, int E){
  int i = blockIdx.x*blockDim.x + threadIdx.x;
  if (i >= E) return;
  int d = dst[i];
  int pos = atomicAdd(&cursor[d], 1);
  ssrc[row_ptr[d] + pos] = src[i];
}

// fhb[N][64](dwords; lane l holds bf16 cols 2l,2l+1) = h @ W (SPLITW: cols 64..127 from Wr).
// elr[n][4] = {el_h0, el_h1, er_h0, er_h1} fused in epilogue.
// Block: 256 thr = 4 waves, 32 rows; wave w: rows 8w..8w+7. Register-safe tile.
template<int IN, int H, bool EMBED, bool SPLITW>
__global__ __launch_bounds__(256) void k_gemm(
    const float* __restrict__ h,
    const int* __restrict__ feat, const float* __restrict__ fv, const float* __restrict__ emb,
    const float* __restrict__ W, const float* __restrict__ Wr,
    const float* __restrict__ al, const float* __restrict__ ar,
    unsigned* __restrict__ fhb, float* __restrict__ elr, int N){
  __shared__ float hs[32][IN + 4];       // [r][k]: b128 broadcast reads along k
  __shared__ float2 Wp[64][64];          // [kk][lane] = (W[:,2l], W[:,2l+1])
  __shared__ int   sfeat[32];
  __shared__ float sfv[32];
  const int t = threadIdx.x;
  const int lane = t & 63, wid = t >> 6;
  const int row0 = blockIdx.x * 32;
  const int wld = SPLITW ? 64 : 128;

  if (EMBED){
    if (t < 32){
      int row = row0 + t;
      sfeat[t] = (row < N) ? feat[row]*64 : 0;
      sfv[t]   = (row < N) ? fv[row] : 0.f;
    }
    __syncthreads();
    for (int id = t; id < 32*(IN/4); id += 256){
      int r = id / (IN/4), c4 = id % (IN/4);
      float4 v = make_float4(0.f,0.f,0.f,0.f);
      if (row0 + r < N){
        v = ((const float4*)(emb + sfeat[r]))[c4];
        float sc = sfv[r];
        v.x *= sc; v.y *= sc; v.z *= sc; v.w *= sc;
      }
      *(float4*)&hs[r][c4*4] = v;
    }
  } else {
    for (int id = t; id < 32*(IN/4); id += 256){
      int r = id / (IN/4), c4 = id % (IN/4);
      int row = row0 + r;
      float4 v = make_float4(0.f,0.f,0.f,0.f);
      if (row < N) v = ((const float4*)(h + (size_t)row*IN))[c4];
      *(float4*)&hs[r][c4*4] = v;
    }
  }

  float2 acc[8];
  #pragma unroll
  for (int j = 0; j < 8; j++) acc[j] = make_float2(0.f, 0.f);

  for (int kb = 0; kb < IN; kb += 64){
    __syncthreads();
    for (int id = t; id < 64*64; id += 256){
      int kk = id >> 6, l = id & 63;
      const float* wb = SPLITW ? (l < 32 ? W + 2*l : Wr + (2*l - 64)) : W + 2*l;
      Wp[kk][l] = *(const float2*)(wb + (size_t)(kb + kk)*wld);
    }
    __syncthreads();
    for (int kk = 0; kk < 64; kk += 4){
      float4 hv[8];
      #pragma unroll
      for (int j = 0; j < 8; j++) hv[j] = *(const float4*)&hs[wid*8 + j][kb + kk];
      #pragma unroll
      for (int u = 0; u < 4; u++){
        float2 wv = Wp[kk + u][lane];
        #pragma unroll
        for (int j = 0; j < 8; j++){
          float x = (&hv[j].x)[u];
          acc[j].x += x * wv.x;
          acc[j].y += x * wv.y;
        }
      }
    }
  }

  // epilogue: bf16 pack-store + fused el/er (heads live in 32-lane halves)
  float2 alv = make_float2(0.f,0.f), arv = make_float2(0.f,0.f);
  if (2*lane < H*64){
    alv = ((const float2*)al)[lane];
    arv = ((const float2*)ar)[lane];
  }
  #pragma unroll
  for (int j = 0; j < 8; j++){
    int row = row0 + wid*8 + j;   // wave-uniform
    if (row >= N) continue;
    unsigned pk = (unsigned)f2bf(acc[j].x) | ((unsigned)f2bf(acc[j].y) << 16);
    fhb[(size_t)row*64 + lane] = pk;
    float pel = acc[j].x*alv.x + acc[j].y*alv.y;
    float per = acc[j].x*arv.x + acc[j].y*arv.y;
    #pragma unroll
    for (int off = 16; off >= 1; off >>= 1){   // reduce within 32-lane halves
      pel += __shfl_xor(pel, off, 64);
      per += __shfl_xor(per, off, 64);
    }
    if (lane == 0){ elr[row*4+0] = pel; elr[row*4+2] = per; }
    if (lane == 32){
      elr[row*4+1] = (H == 2) ? pel : 0.f;
      elr[row*4+3] = (H == 2) ? per : 0.f;
    }
  }
}

// One wave per dst node. Pass 1: flat exp-sum (no max; logits bounded, clamp 30).
// Pass 2: readlane broadcast + 8-deep gather; first chunk reuses pass-1 numerators.
template<int H>
__global__ __launch_bounds__(256) void k_agg(
    const unsigned* __restrict__ fhb, const float* __restrict__ elr,
    const int* __restrict__ row_ptr, const int* __restrict__ ssrc,
    const float* __restrict__ bias, const float* __restrict__ res,
    int act, int res_from_fh,
    float* __restrict__ out, int out_ld, int N){
  int lane = threadIdx.x & 63, wid = threadIdx.x >> 6;
  int n = blockIdx.x*4 + wid;
  if (n >= N) return;
  int beg = row_ptr[n], end = row_ptr[n+1];
  float er0 = elr[n*4+2];
  float er1 = (H == 2) ? elr[n*4+3] : 0.f;

  // pass 1: numerators + denominator (softmax is shift-invariant; no max needed)
  float x0 = 0.f, x1 = 0.f;
  {
    int i = beg + lane;
    if (i < end){
      int s = ssrc[i];
      float2 el = *(const float2*)(elr + s*4);
      x0 = __expf(fminf(lrelu(el.x + er0), 30.f));
      if (H == 2) x1 = __expf(fminf(lrelu(el.y + er1), 30.f));
    }
  }
  float d0 = x0, d1 = x1;
  for (int i = beg + lane + 64; i < end; i += 64){
    int s = ssrc[i];
    float2 el = *(const float2*)(elr + s*4);
    d0 += __expf(fminf(lrelu(el.x + er0), 30.f));
    if (H == 2) d1 += __expf(fminf(lrelu(el.y + er1), 30.f));
  }
  #pragma unroll
  for (int off = 32; off >= 1; off >>= 1){       // add-only butterfly
    d0 += __shfl_xor(d0, off, 64);
    if (H == 2) d1 += __shfl_xor(d1, off, 64);
  }
  float rd0 = d0 > 0.f ? 1.f/d0 : 0.f;
  float rd1 = (H == 2 && d1 > 0.f) ? 1.f/d1 : 0.f;

  // pass 2
  float ax = 0.f, ay = 0.f;
  for (int base = beg; base < end; base += 64){
    int i = base + lane;
    int s = 0; float a0 = 0.f, a1 = 0.f;
    if (i < end){
      s = ssrc[i];
      if (base == beg){
        a0 = x0 * rd0; if (H == 2) a1 = x1 * rd1;
      } else {
        float2 el = *(const float2*)(elr + s*4);
        a0 = __expf(fminf(lrelu(el.x + er0), 30.f)) * rd0;
        if (H == 2) a1 = __expf(fminf(lrelu(el.y + er1), 30.f)) * rd1;
      }
    }
    int cnt  = min(64, end - base);
    int cnt8 = (cnt + 7) & ~7;          // pad lanes have a=0, s=0 -> contribute 0
    if (H == 2){
      for (int j0 = 0; j0 < cnt8; j0 += 8){
        unsigned w[8]; float aj[8];
        #pragma unroll
        for (int u = 0; u < 8; u++){
          int sj = __builtin_amdgcn_readlane(s, j0 + u);      // SGPR: scalar addr
          w[u] = fhb[(size_t)sj*64 + lane];                   // cols 2l,2l+1
        }
        #pragma unroll
        for (int u = 0; u < 8; u++){
          float aj0 = rl_f(a0, j0 + u);
          float aj1 = rl_f(a1, j0 + u);
          aj[u] = (lane < 32) ? aj0 : aj1;                    // head = 2l/64
        }
        #pragma unroll
        for (int u = 0; u < 8; u++){
          ax += bf2f((unsigned short)(w[u] & 0xffffu)) * aj[u];
          ay += bf2f((unsigned short)(w[u] >> 16))     * aj[u];
        }
      }
    } else {
      const unsigned short* fh16 = (const unsigned short*)fhb;
      for (int j0 = 0; j0 < cnt8; j0 += 8){
        unsigned short w[8]; float aj[8];
        #pragma unroll
        for (int u = 0; u < 8; u++){
          int sj = __builtin_amdgcn_readlane(s, j0 + u);
          w[u] = fh16[(size_t)sj*128 + lane];                 // cols 0..63
        }
        #pragma unroll
        for (int u = 0; u < 8; u++) aj[u] = rl_f(a0, j0 + u);
        #pragma unroll
        for (int u = 0; u < 8; u++) ax += bf2f(w[u]) * aj[u];
      }
    }
  }
  if (H == 2){
    int c0 = lane*2;
    float o0 = ax + bias[c0], o1 = ay + bias[c0+1];
    if (res){ o0 += res[n*128 + c0]; o1 += res[n*128 + c0+1]; }
    if (act){ o0 = o0 > 0.f ? o0 : expm1f(o0); o1 = o1 > 0.f ? o1 : expm1f(o1); }
    *(float2*)(out + n*out_ld + c0) = make_float2(o0, o1);
  } else {
    const unsigned short* fh16 = (const unsigned short*)fhb;
    float o = ax + bias[lane];
    if (res_from_fh) o += bf2f(fh16[(size_t)n*128 + 64 + lane]);
    out[n*out_ld + lane] = o;
  }
}

extern "C" void kernel_launch(void* const* d_in, const int* in_sizes, int n_in,
                              void* d_out, int out_size, void* d_ws, size_t ws_size,
                              hipStream_t stream) {
  const int*   feat = (const int*)  d_in[0];
  const float* fv   = (const float*)d_in[1];
  const int*   src  = (const int*)  d_in[2];
  const int*   dst  = (const int*)  d_in[3];
  const float* emb  = (const float*)d_in[4];
  const float* W0   = (const float*)d_in[5];
  const float* al0  = (const float*)d_in[6];
  const float* ar0  = (const float*)d_in[7];
  const float* b0   = (const float*)d_in[8];
  const float* W1   = (const float*)d_in[9];
  const float* al1  = (const float*)d_in[10];
  const float* ar1  = (const float*)d_in[11];
  const float* b1   = (const float*)d_in[12];
  const float* W2   = (const float*)d_in[13];
  const float* al2  = (const float*)d_in[14];
  const float* ar2  = (const float*)d_in[15];
  const float* b2   = (const float*)d_in[16];
  const float* rW2  = (const float*)d_in[17];
  const int N = in_sizes[0] / 8;   // 50000
  const int E = in_sizes[2];       // 800000

  size_t off = 0;
  auto alloc = [&](size_t bytes) -> void* {
    void* p = (char*)d_ws + off;
    off = (off + bytes + 255) & ~(size_t)255;
    return p;
  };
  unsigned* P1  = (unsigned*)alloc((size_t)N*64*sizeof(unsigned));   // fh bf16 packed
  float* P2     = (float*)alloc((size_t)N*128*sizeof(float));
  float* P3     = (float*)alloc((size_t)N*128*sizeof(float));
  float* elr    = (float*)alloc((size_t)N*4*sizeof(float));
  int* row_ptr  = (int*)alloc((size_t)(N+1)*sizeof(int));
  int* counts   = (int*)alloc((size_t)2*N*sizeof(int));
  int* cursor   = counts + N;
  int* ssrc     = (int*)alloc((size_t)E*sizeof(int));
  int* bsum     = (int*)alloc(256*sizeof(int));

  int nb1 = (N + 255) / 256;
  // CSR build
  k_zero_i32<<<(2*N + 255)/256, 256, 0, stream>>>(counts, 2*N);
  k_hist<<<(E + 255)/256, 256, 0, stream>>>(dst, counts, E);
  k_scan_local<<<nb1, 256, 0, stream>>>(counts, row_ptr, bsum, N);
  k_scan_top<<<1, 256, 0, stream>>>(bsum, nb1);
  k_scan_fix<<<nb1, 256, 0, stream>>>(row_ptr, bsum, N);
  k_scatter<<<(E + 255)/256, 256, 0, stream>>>(src, dst, row_ptr, cursor, ssrc, E);

  int gt = (N + 31)/32;
  int nagg = (N + 3)/4;
  // layer 0: in=64 (fused embedding), H=2, no residual, elu
  k_gemm<64,2,true,false><<<gt, 256, 0, stream>>>(nullptr, feat, fv, emb,
      W0, nullptr, al0, ar0, P1, elr, N);
  k_agg<2><<<nagg, 256, 0, stream>>>(P1, elr, row_ptr, ssrc, b0, nullptr, 1, 0, P2, 128, N);
  // layer 1: in=128, H=2, identity residual, elu
  k_gemm<128,2,false,false><<<gt, 256, 0, stream>>>(P2, nullptr, nullptr, nullptr,
      W1, nullptr, al1, ar1, P1, elr, N);
  k_agg<2><<<nagg, 256, 0, stream>>>(P1, elr, row_ptr, ssrc, b1, P2, 1, 0, P3, 128, N);
  // layer 2: in=128, H=1, projected residual (cols 64..127 = h@resW2), no act
  k_gemm<128,1,false,true><<<gt, 256, 0, stream>>>(P3, nullptr, nullptr, nullptr,
      W2, rW2, al2, ar2, P1, elr, N);
  k_agg<1><<<nagg, 256, 0, stream>>>(P1, elr, row_ptr, ssrc, b2, nullptr, 0, 1, (float*)d_out, 64, N);
}

// Round 6
// 367.364 us; speedup vs baseline: 2.0027x; 1.2246x over previous
//
#include <hip/hip_runtime.h>

// GAT (3-layer) on MI355X. N=50000 nodes, E=800000 edges, D=64, H=2/2/1.
// R6: GEMMs moved to v_mfma_f32_16x16x32_bf16 (A=h bf16 from global, B=Wt bf16
//     in LDS w/ +8 pad), fused el/er epilogue; agg emits bf16 h-copy for the
//     next layer. fp32 GEMM had a ~60us vector-ALU/latency floor (R5: VALU 29%,
//     occ 25%); MFMA floor is ~5us. agg unchanged from R5 (fhb layout identical).

typedef __attribute__((ext_vector_type(8))) short short8;   // 8 bf16 (4 VGPRs)
typedef __attribute__((ext_vector_type(4))) float float4v;  // 4 fp32 acc

__device__ __forceinline__ float lrelu(float x){ return x >= 0.f ? x : 0.2f*x; }

__device__ __forceinline__ unsigned short f2bf(float f){   // RNE round
  unsigned int u = __float_as_uint(f);
  u += 0x7fffu + ((u >> 16) & 1u);
  return (unsigned short)(u >> 16);
}
__device__ __forceinline__ float bf2f(unsigned short u){
  return __uint_as_float((unsigned int)u << 16);
}
__device__ __forceinline__ float rl_f(float v, int l){
  return __int_as_float(__builtin_amdgcn_readlane(__float_as_int(v), l));
}

__global__ void k_zero_i32(int* __restrict__ p, int n){
  int i = blockIdx.x*blockDim.x + threadIdx.x;
  if (i < n) p[i] = 0;
}

__global__ void k_hist(const int* __restrict__ dst, int* __restrict__ counts, int E){
  int i = blockIdx.x*blockDim.x + threadIdx.x;
  if (i < E) atomicAdd(&counts[dst[i]], 1);
}

__global__ void k_scan_local(const int* __restrict__ counts, int* __restrict__ row_ptr,
                             int* __restrict__ bsum, int N){
  __shared__ int s[256];
  int t = threadIdx.x, g = blockIdx.x*256 + t;
  int v = (g < N) ? counts[g] : 0;
  s[t] = v; __syncthreads();
  #pragma unroll
  for (int off = 1; off < 256; off <<= 1){
    int x = 0;
    if (t >= off) x = s[t-off];
    __syncthreads();
    s[t] += x;
    __syncthreads();
  }
  if (g < N) row_ptr[g+1] = s[t];
  if (g == 0 && t == 0) row_ptr[0] = 0;
  if (t == 255) bsum[blockIdx.x] = s[255];
}

__global__ void k_scan_top(int* __restrict__ bsum, int nb){
  __shared__ int s[256];
  int t = threadIdx.x;
  int v = (t < nb) ? bsum[t] : 0;
  s[t] = v; __syncthreads();
  #pragma unroll
  for (int off = 1; off < 256; off <<= 1){
    int x = 0;
    if (t >= off) x = s[t-off];
    __syncthreads();
    s[t] += x;
    __syncthreads();
  }
  if (t < nb) bsum[t] = s[t] - v;  // exclusive block offsets
}

__global__ void k_scan_fix(int* __restrict__ row_ptr, const int* __restrict__ bsum, int N){
  int g = blockIdx.x*256 + threadIdx.x;
  if (g < N && blockIdx.x > 0) row_ptr[g+1] += bsum[blockIdx.x];
}

__global__ void k_scatter(const int* __restrict__ src, const int* __restrict__ dst,
                          const int* __restrict__ row_ptr, int* __restrict__ cursor,
                          int* __restrict__ ssrc, int E){
  int i = blockIdx.x*blockDim.x + threadIdx.x;
  if (i >= E) return;
  int d = dst[i];
  int pos = atomicAdd(&cursor[d], 1);
  ssrc[row_ptr[d] + pos] = src[i];
}

// Wt[n][IN] bf16 = W[k][n] transposed. Wb!=null: cols 0..63 from Wa[k][64], 64..127 from Wb.
__global__ void k_wprep(const float* __restrict__ Wa, const float* __restrict__ Wb,
                        int IN, unsigned short* __restrict__ Wt){
  int id = blockIdx.x*256 + threadIdx.x;
  if (id >= 128*IN) return;
  int n = id / IN, k = id % IN;
  float v;
  if (Wb) v = (n < 64) ? Wa[k*64 + n] : Wb[k*64 + (n - 64)];
  else    v = Wa[k*128 + n];
  Wt[n*IN + k] = f2bf(v);
}

// h0b[N][64] bf16 = (emb[feat[n]] * fv[n])
__global__ void k_embed(const int* __restrict__ feat, const float* __restrict__ fv,
                        const float* __restrict__ emb, unsigned int* __restrict__ h0b, int N){
  int t = blockIdx.x*blockDim.x + threadIdx.x;   // N*16 threads, 4 cols each
  int n = t >> 4, c4 = t & 15;
  if (n >= N) return;
  float4 v = ((const float4*)(emb + (size_t)feat[n]*64))[c4];
  float sc = fv[n];
  unsigned int p0 = (unsigned)f2bf(v.x*sc) | ((unsigned)f2bf(v.y*sc) << 16);
  unsigned int p1 = (unsigned)f2bf(v.z*sc) | ((unsigned)f2bf(v.w*sc) << 16);
  h0b[(size_t)n*32 + c4*2]     = p0;
  h0b[(size_t)n*32 + c4*2 + 1] = p1;
}

// MFMA GEMM: fhb[N][128](bf16 row-major) = hb[N][IN](bf16) @ W(128 cols via Wt).
// Block 256 thr = 4 waves; wave computes 16 rows x 128 cols (8 accs, IN/32 K-steps).
// Layouts (verified): A[m=lane&15][k=quad*8+j]; B[k=quad*8+j][n=lane&15];
// D: col=lane&15, row=quad*4+reg. el/er fused (16-lane butterfly per quad).
template<int IN, int H>
__global__ __launch_bounds__(256) void k_gemm_mfma(
    const unsigned short* __restrict__ hb,   // [N][IN] bf16
    const unsigned short* __restrict__ Wt,   // [128][IN] bf16, n-major
    const float* __restrict__ al, const float* __restrict__ ar,
    unsigned short* __restrict__ fhb,        // [N][128] bf16
    float* __restrict__ elr, int N){
  constexpr int KS = IN/32;
  constexpr int LDP = IN + 8;                // +8 bf16 pad: 272B row stride, 2-way banks
  __shared__ unsigned short Wt_s[128*LDP];
  const int t = threadIdx.x;
  const int lane = t & 63, wid = t >> 6;
  const int l15 = lane & 15, quad = lane >> 4;
  const int row0 = blockIdx.x*64 + wid*16;

  // stage Wt -> LDS (uint4 = 8 bf16)
  for (int id = t; id < 128*(IN/8); id += 256){
    int r = id/(IN/8), seg = id%(IN/8);
    ((uint4*)(Wt_s + r*LDP))[seg] = ((const uint4*)(Wt + (size_t)r*IN))[seg];
  }
  // A fragments from global (overlaps LDS staging)
  short8 a[KS];
  int arow = row0 + l15;
  #pragma unroll
  for (int s = 0; s < KS; s++){
    if (arow < N) a[s] = *(const short8*)(hb + (size_t)arow*IN + s*32 + quad*8);
    else          a[s] = short8{0,0,0,0,0,0,0,0};
  }
  __syncthreads();

  float4v acc[8];
  #pragma unroll
  for (int nt = 0; nt < 8; nt++) acc[nt] = float4v{0.f,0.f,0.f,0.f};
  #pragma unroll
  for (int nt = 0; nt < 8; nt++){
    #pragma unroll
    for (int s = 0; s < KS; s++){
      short8 b = *(const short8*)(Wt_s + (nt*16 + l15)*LDP + s*32 + quad*8);
      acc[nt] = __builtin_amdgcn_mfma_f32_16x16x32_bf16(a[s], b, acc[nt], 0, 0, 0);
    }
  }

  // al/ar at this lane's columns (col = nt*16 + l15); H==1: heads>0 are zero
  float alc[8], arc[8];
  #pragma unroll
  for (int nt = 0; nt < 8; nt++){
    bool hv = (H == 2) || (nt < 4);
    alc[nt] = hv ? al[nt*16 + l15] : 0.f;
    arc[nt] = hv ? ar[nt*16 + l15] : 0.f;
  }
  #pragma unroll
  for (int reg = 0; reg < 4; reg++){
    int row = row0 + quad*4 + reg;
    bool rv = row < N;
    if (rv){
      #pragma unroll
      for (int nt = 0; nt < 8; nt++)
        fhb[(size_t)row*128 + nt*16 + l15] = f2bf(acc[nt][reg]);
    }
    float pel0 = 0.f, per0 = 0.f, pel1 = 0.f, per1 = 0.f;
    #pragma unroll
    for (int nt = 0; nt < 4; nt++){
      pel0 += acc[nt][reg]*alc[nt];     per0 += acc[nt][reg]*arc[nt];
      pel1 += acc[nt+4][reg]*alc[nt+4]; per1 += acc[nt+4][reg]*arc[nt+4];
    }
    #pragma unroll
    for (int off = 1; off < 16; off <<= 1){   // reduce across the 16 lanes of a quad
      pel0 += __shfl_xor(pel0, off, 64);
      pel1 += __shfl_xor(pel1, off, 64);
      per0 += __shfl_xor(per0, off, 64);
      per1 += __shfl_xor(per1, off, 64);
    }
    if (l15 == 0 && rv){
      elr[row*4+0] = pel0;
      elr[row*4+1] = (H == 2) ? pel1 : 0.f;
      elr[row*4+2] = per0;
      elr[row*4+3] = (H == 2) ? per1 : 0.f;
    }
  }
}

// One wave per dst node. Pass 1: flat exp-sum (no max; logits bounded, clamp 30).
// Pass 2: readlane broadcast + 8-deep gather. Optionally emits bf16 copy of out.
template<int H>
__global__ __launch_bounds__(256) void k_agg(
    const unsigned* __restrict__ fhb, const float* __restrict__ elr,
    const int* __restrict__ row_ptr, const int* __restrict__ ssrc,
    const float* __restrict__ bias, const float* __restrict__ res,
    int act, int res_from_fh,
    float* __restrict__ out, int out_ld, unsigned* __restrict__ outb, int N){
  int lane = threadIdx.x & 63, wid = threadIdx.x >> 6;
  int n = blockIdx.x*4 + wid;
  if (n >= N) return;
  int beg = row_ptr[n], end = row_ptr[n+1];
  float er0 = elr[n*4+2];
  float er1 = (H == 2) ? elr[n*4+3] : 0.f;

  // pass 1: numerators + denominator (softmax is shift-invariant; no max needed)
  float x0 = 0.f, x1 = 0.f;
  {
    int i = beg + lane;
    if (i < end){
      int s = ssrc[i];
      float2 el = *(const float2*)(elr + s*4);
      x0 = __expf(fminf(lrelu(el.x + er0), 30.f));
      if (H == 2) x1 = __expf(fminf(lrelu(el.y + er1), 30.f));
    }
  }
  float d0 = x0, d1 = x1;
  for (int i = beg + lane + 64; i < end; i += 64){
    int s = ssrc[i];
    float2 el = *(const float2*)(elr + s*4);
    d0 += __expf(fminf(lrelu(el.x + er0), 30.f));
    if (H == 2) d1 += __expf(fminf(lrelu(el.y + er1), 30.f));
  }
  #pragma unroll
  for (int off = 32; off >= 1; off >>= 1){       // add-only butterfly
    d0 += __shfl_xor(d0, off, 64);
    if (H == 2) d1 += __shfl_xor(d1, off, 64);
  }
  float rd0 = d0 > 0.f ? 1.f/d0 : 0.f;
  float rd1 = (H == 2 && d1 > 0.f) ? 1.f/d1 : 0.f;

  // pass 2
  float ax = 0.f, ay = 0.f;
  for (int base = beg; base < end; base += 64){
    int i = base + lane;
    int s = 0; float a0 = 0.f, a1 = 0.f;
    if (i < end){
      s = ssrc[i];
      if (base == beg){
        a0 = x0 * rd0; if (H == 2) a1 = x1 * rd1;
      } else {
        float2 el = *(const float2*)(elr + s*4);
        a0 = __expf(fminf(lrelu(el.x + er0), 30.f)) * rd0;
        if (H == 2) a1 = __expf(fminf(lrelu(el.y + er1), 30.f)) * rd1;
      }
    }
    int cnt  = min(64, end - base);
    int cnt8 = (cnt + 7) & ~7;          // pad lanes have a=0, s=0 -> contribute 0
    if (H == 2){
      for (int j0 = 0; j0 < cnt8; j0 += 8){
        unsigned w[8]; float aj[8];
        #pragma unroll
        for (int u = 0; u < 8; u++){
          int sj = __builtin_amdgcn_readlane(s, j0 + u);      // SGPR: scalar addr
          w[u] = fhb[(size_t)sj*64 + lane];                   // cols 2l,2l+1
        }
        #pragma unroll
        for (int u = 0; u < 8; u++){
          float aj0 = rl_f(a0, j0 + u);
          float aj1 = rl_f(a1, j0 + u);
          aj[u] = (lane < 32) ? aj0 : aj1;                    // head = 2l/64
        }
        #pragma unroll
        for (int u = 0; u < 8; u++){
          ax += bf2f((unsigned short)(w[u] & 0xffffu)) * aj[u];
          ay += bf2f((unsigned short)(w[u] >> 16))     * aj[u];
        }
      }
    } else {
      const unsigned short* fh16 = (const unsigned short*)fhb;
      for (int j0 = 0; j0 < cnt8; j0 += 8){
        unsigned short w[8]; float aj[8];
        #pragma unroll
        for (int u = 0; u < 8; u++){
          int sj = __builtin_amdgcn_readlane(s, j0 + u);
          w[u] = fh16[(size_t)sj*128 + lane];                 // cols 0..63
        }
        #pragma unroll
        for (int u = 0; u < 8; u++) aj[u] = rl_f(a0, j0 + u);
        #pragma unroll
        for (int u = 0; u < 8; u++) ax += bf2f(w[u]) * aj[u];
      }
    }
  }
  if (H == 2){
    int c0 = lane*2;
    float o0 = ax + bias[c0], o1 = ay + bias[c0+1];
    if (res){ o0 += res[n*128 + c0]; o1 += res[n*128 + c0+1]; }
    if (act){ o0 = o0 > 0.f ? o0 : expm1f(o0); o1 = o1 > 0.f ? o1 : expm1f(o1); }
    *(float2*)(out + n*out_ld + c0) = make_float2(o0, o1);
    if (outb) outb[(size_t)n*64 + lane] = (unsigned)f2bf(o0) | ((unsigned)f2bf(o1) << 16);
  } else {
    const unsigned short* fh16 = (const unsigned short*)fhb;
    float o = ax + bias[lane];
    if (res_from_fh) o += bf2f(fh16[(size_t)n*128 + 64 + lane]);
    out[n*out_ld + lane] = o;
  }
}

extern "C" void kernel_launch(void* const* d_in, const int* in_sizes, int n_in,
                              void* d_out, int out_size, void* d_ws, size_t ws_size,
                              hipStream_t stream) {
  const int*   feat = (const int*)  d_in[0];
  const float* fv   = (const float*)d_in[1];
  const int*   src  = (const int*)  d_in[2];
  const int*   dst  = (const int*)  d_in[3];
  const float* emb  = (const float*)d_in[4];
  const float* W0   = (const float*)d_in[5];
  const float* al0  = (const float*)d_in[6];
  const float* ar0  = (const float*)d_in[7];
  const float* b0   = (const float*)d_in[8];
  const float* W1   = (const float*)d_in[9];
  const float* al1  = (const float*)d_in[10];
  const float* ar1  = (const float*)d_in[11];
  const float* b1   = (const float*)d_in[12];
  const float* W2   = (const float*)d_in[13];
  const float* al2  = (const float*)d_in[14];
  const float* ar2  = (const float*)d_in[15];
  const float* b2   = (const float*)d_in[16];
  const float* rW2  = (const float*)d_in[17];
  const int N = in_sizes[0] / 8;   // 50000
  const int E = in_sizes[2];       // 800000

  size_t off = 0;
  auto alloc = [&](size_t bytes) -> void* {
    void* p = (char*)d_ws + off;
    off = (off + bytes + 255) & ~(size_t)255;
    return p;
  };
  unsigned short* P1 = (unsigned short*)alloc((size_t)N*128*sizeof(unsigned short)); // fhb
  float* P2     = (float*)alloc((size_t)N*128*sizeof(float));
  float* P3     = (float*)alloc((size_t)N*128*sizeof(float));
  unsigned short* hb = (unsigned short*)alloc((size_t)N*128*sizeof(unsigned short)); // h bf16
  float* elr    = (float*)alloc((size_t)N*4*sizeof(float));
  int* row_ptr  = (int*)alloc((size_t)(N+1)*sizeof(int));
  int* counts   = (int*)alloc((size_t)2*N*sizeof(int));
  int* cursor   = counts + N;
  int* ssrc     = (int*)alloc((size_t)E*sizeof(int));
  int* bsum     = (int*)alloc(256*sizeof(int));
  unsigned short* Wt0 = (unsigned short*)alloc((size_t)128*64*sizeof(unsigned short));
  unsigned short* Wt1 = (unsigned short*)alloc((size_t)128*128*sizeof(unsigned short));
  unsigned short* Wt2 = (unsigned short*)alloc((size_t)128*128*sizeof(unsigned short));

  int nb1 = (N + 255) / 256;
  // CSR build
  k_zero_i32<<<(2*N + 255)/256, 256, 0, stream>>>(counts, 2*N);
  k_hist<<<(E + 255)/256, 256, 0, stream>>>(dst, counts, E);
  k_scan_local<<<nb1, 256, 0, stream>>>(counts, row_ptr, bsum, N);
  k_scan_top<<<1, 256, 0, stream>>>(bsum, nb1);
  k_scan_fix<<<nb1, 256, 0, stream>>>(row_ptr, bsum, N);
  k_scatter<<<(E + 255)/256, 256, 0, stream>>>(src, dst, row_ptr, cursor, ssrc, E);
  // weight transpose+bf16 prep, embedding gather
  k_wprep<<<(128*64 + 255)/256, 256, 0, stream>>>(W0, nullptr, 64, Wt0);
  k_wprep<<<(128*128 + 255)/256, 256, 0, stream>>>(W1, nullptr, 128, Wt1);
  k_wprep<<<(128*128 + 255)/256, 256, 0, stream>>>(W2, rW2, 128, Wt2);
  k_embed<<<(N*16 + 255)/256, 256, 0, stream>>>(feat, fv, emb, (unsigned int*)hb, N);

  int gt = (N + 63)/64;
  int nagg = (N + 3)/4;
  // layer 0: in=64, H=2, no residual, elu
  k_gemm_mfma<64,2><<<gt, 256, 0, stream>>>(hb, Wt0, al0, ar0, P1, elr, N);
  k_agg<2><<<nagg, 256, 0, stream>>>((unsigned*)P1, elr, row_ptr, ssrc, b0, nullptr,
                                     1, 0, P2, 128, (unsigned*)hb, N);
  // layer 1: in=128, H=2, identity residual, elu
  k_gemm_mfma<128,2><<<gt, 256, 0, stream>>>(hb, Wt1, al1, ar1, P1, elr, N);
  k_agg<2><<<nagg, 256, 0, stream>>>((unsigned*)P1, elr, row_ptr, ssrc, b1, P2,
                                     1, 0, P3, 128, (unsigned*)hb, N);
  // layer 2: in=128, H=1, projected residual (fh cols 64..127 = h@resW2), no act
  k_gemm_mfma<128,1><<<gt, 256, 0, stream>>>(hb, Wt2, al2, ar2, P1, elr, N);
  k_agg<1><<<nagg, 256, 0, stream>>>((unsigned*)P1, elr, row_ptr, ssrc, b2, nullptr,
                                     0, 1, (float*)d_out, 64, nullptr, N);
}